// Round 15
// baseline (266.439 us; speedup 1.0000x reference)
//
#include <hip/hip_runtime.h>

typedef unsigned short u16;
typedef __attribute__((ext_vector_type(8))) short s16x8;   // 8 x bf16 frag (verified form)
typedef __attribute__((ext_vector_type(4))) float floatx4;

// xt (per batch): [cg=16][row=66][col=66][c32=32] bf16, spatial-padded NCHW32c,
// holding x * style (style folded in). SWIZZLED: 16B slot ^= (col>>1)&3.
#define XT_ROWELEMS 2112                 // 66*32
#define XT_CGELEMS  139392               // 66*66*32
#define XT_PB       4460544ull           // 16*66*66*32*2 bytes per batch
// wb (batch-INDEPENDENT): [t=9][cg=16][o512=512][c32=32] bf16 = w*gain.
// SWIZZLED: within each 64B o-row, c32 index ^= ((o>>1)&3)<<3
#define WB_B        4718592ull           // 9*16*512*32*2 bytes
#define SIG_B       16384ull             // sigma_inv[8][512] fp32

// async global->LDS DMA, 16B per lane; lds dest = wave-uniform base + lane*16
#define GLDS(gp, lp) __builtin_amdgcn_global_load_lds(                      \
    (const __attribute__((address_space(1))) void*)(gp),                    \
    (__attribute__((address_space(3))) void*)(lp), 16, 0, 0)

__device__ __forceinline__ u16 f2bf(float f) {
  union { float f; unsigned u; } x; x.f = f;
  unsigned r = x.u + 0x7fffu + ((x.u >> 16) & 1u);
  return (u16)(r >> 16);
}

// ---------------- fused producer: transpose(x*style) + weight-convert + sigma ----------------
// grid 8704, 256 threads. Roles: bid%17==0 -> W (512 blocks, one per o);
// else T (8192 blocks: 1024 tiles x 8 batches). Interleaved for co-residency.
// W role: wb[o] = bf16(w[o]*gain) in conv layout (swizzled), PLUS
//   sigma_inv[b][o] = rsqrt(sum_{ci,t}(w*gain*style[b,ci])^2 + 1e-8) for all 8 b
//   (exact reference arithmetic, fp32).
// T role: xt[b] = bf16(fm[b,ci] * style[b,ci]) — conv is bilinear, so
//   conv(x*s, w*gain)*sinv == conv(x, w*gain*s*sinv) exactly.
__global__ __launch_bounds__(256) void prep_fused(
    const float* __restrict__ fm, const float* __restrict__ w,
    const float* __restrict__ style, u16* __restrict__ xt,
    u16* __restrict__ wb, float* __restrict__ sig)
{
  __shared__ __align__(16) char smraw[34944];     // W: 4608+4096+32 f32 | T: 64x40 u16
  const int bid = blockIdx.x;
  const int tid = threadIdx.x;
  const int g = bid / 17, rrole = bid - g * 17;

  if (rrole != 0) {
    // ---------- T role: transpose with style fold ----------
    u16* sm16 = (u16*)smraw;                      // [x=64][ci=32] pad 40
    const int ti = g * 16 + (rrole - 1);          // [0, 8192)
    const int y = ti & 63, cgi = (ti >> 6) & 15, bl = ti >> 10;
    const float* src = fm + (((size_t)bl * 512 + cgi * 32) * 64 + y) * 64;
    const float* stp = style + bl * 512 + cgi * 32;
    const int x4 = (tid & 15) * 4;
#pragma unroll
    for (int it = 0; it < 2; ++it) {
      int ci = (tid >> 4) + it * 16;
      float sval = stp[ci];
      float4 v = *(const float4*)&src[(size_t)ci * 4096 + x4];   // 16B/lane coalesced
      sm16[(x4 + 0) * 40 + ci] = f2bf(v.x * sval);
      sm16[(x4 + 1) * 40 + ci] = f2bf(v.y * sval);
      sm16[(x4 + 2) * 40 + ci] = f2bf(v.z * sval);
      sm16[(x4 + 3) * 40 + ci] = f2bf(v.w * sval);
    }

    u16* cgbase = xt + (size_t)(bl * 16 + cgi) * XT_CGELEMS;
    const uint4 z = {0u, 0u, 0u, 0u};
    u16* rowb = cgbase + (size_t)(y + 1) * XT_ROWELEMS;
    if (tid < 4)              ((uint4*)rowb)[tid] = z;                  // col 0
    else if (tid < 8)         ((uint4*)(rowb + 65 * 32))[tid - 4] = z;  // col 65
    if (y == 0)  for (int i = tid; i < 264; i += 256) ((uint4*)cgbase)[i] = z;
    if (y == 63) for (int i = tid; i < 264; i += 256) ((uint4*)(cgbase + 65 * XT_ROWELEMS))[i] = z;

    __syncthreads();
    const int x = tid >> 2;
    uint4 u = *(const uint4*)&sm16[x * 40 + (tid & 3) * 8];       // one ds_read_b128
    const int col = 1 + x;
    const int slot = (tid & 3) ^ ((col >> 1) & 3);                // pre-swizzle
    ((uint4*)rowb)[col * 4 + slot] = u;
  } else {
    // ---------- W role: one o; wb = bf16(w*gain); sigma_inv for 8 batches ----------
    float* sv = (float*)smraw;                    // 4608: w[o]*gain, idx = ci*9 + t
    float* s2 = sv + 4608;                        // 4096: style^2 for 8 batches
    float* red = s2 + 4096;                       // 32: per-wave partials x 8 b
    const int o = g;
    const float gain = 0.014731391f;              // 1/sqrt(512*9)
    const float* wo = w + (size_t)o * 4608;
    for (int i = tid; i < 4096; i += 256) { float s = style[i]; s2[i] = s * s; }
    __syncthreads();

    float ss[8];
#pragma unroll
    for (int b = 0; b < 8; ++b) ss[b] = 0.f;
#pragma unroll
    for (int j = 0; j < 5; ++j) {                 // 1152 float4 slots over 256 thr
      int s4 = j * 256 + tid;
      if (s4 < 1152) {
        float4 v = *(const float4*)&wo[s4 * 4];   // 16B/lane coalesced
        int i0 = s4 * 4;
        int c0 = i0 / 9, rem = i0 - c0 * 9;       // ci of elem 0
        int ci1 = c0 + (rem + 1 >= 9), ci2 = c0 + (rem + 2 >= 9), ci3 = c0 + (rem + 3 >= 9);
        floatx4 wv = {v.x * gain, v.y * gain, v.z * gain, v.w * gain};
        ((floatx4*)sv)[s4] = wv;                  // ds_write_b128
        float q0 = wv[0] * wv[0], q1 = wv[1] * wv[1];
        float q2 = wv[2] * wv[2], q3 = wv[3] * wv[3];
#pragma unroll
        for (int b = 0; b < 8; ++b) {
          const float* sb = s2 + b * 512;
          ss[b] += q0 * sb[c0] + q1 * sb[ci1] + q2 * sb[ci2] + q3 * sb[ci3];
        }
      }
    }
    const int lane = tid & 63, wave = tid >> 6;
#pragma unroll
    for (int b = 0; b < 8; ++b) {
#pragma unroll
      for (int off = 32; off > 0; off >>= 1) ss[b] += __shfl_down(ss[b], off, 64);
    }
    if (lane == 0)
#pragma unroll
      for (int b = 0; b < 8; ++b) red[wave * 8 + b] = ss[b];
    __syncthreads();
    if (tid < 8) {
      float t8 = red[tid] + red[8 + tid] + red[16 + tid] + red[24 + tid];
      sig[tid * 512 + o] = rsqrtf(t8 + 1e-8f);    // sigma_inv[b][o]
    }

    // wb store: [t][cg][o][c32], swizzled o-row; NO style, NO sinv (hoisted out)
    const int axor = ((o >> 1) & 3) << 3;
    u16* base = wb + (size_t)o * 32;
    const int c0 = tid * 2;                       // even -> XOR keeps pair adjacent
    const int pos = (c0 & 31) ^ axor;             // even (axor has no bit0)
#pragma unroll
    for (int t = 0; t < 9; ++t) {                 // 9 paired u32 stores
      unsigned lo = f2bf(sv[c0 * 9 + t]);
      unsigned hi = f2bf(sv[(c0 + 1) * 9 + t]);
      *(unsigned*)(base + ((size_t)(t * 16 + (c0 >> 5))) * 16384 + pos) = lo | (hi << 16);
    }
  }
}

// ---------------- conv: R6-verified body + sigma epilogue (session best: 261.6 total) ----------------
// 256x128 C tile, 256 threads = 4 waves, wave tile 128x64, 16x16x32 MFMA, plain
// __syncthreads discipline. Cross-session ledger: this form = 158.4/162.4/160.3 us;
// counted-vmcnt form = 157.8/170.2 — plain form has the better mean; schedule
// dimension closed. wb is batch-independent (L2-resident; FETCH == xt only).
// R15 epsilon: sigma preload hoisted to prologue (tail barrier+load removed);
// last-step trailing barrier guarded out (no LDS consumer after it).
__global__ __launch_bounds__(256, 2) void conv_mfma(
    const u16* __restrict__ wb, const u16* __restrict__ xt,
    const float* __restrict__ sig, float* __restrict__ out)
{
  const int id = blockIdx.x;
  const int bl = id & 7;                            // same batch -> same XCD (round robin)
  const int rest = id >> 3;
  const int og = rest & 1, p_blk = rest >> 1;       // og: 256-row M chunk; p_blk: 128 px
  const int tid = threadIdx.x;
  const int lane = tid & 63, wave = tid >> 6;
  const int wm_off = (wave & 1) * 128, wn_off = (wave >> 1) * 64;
  const int l15 = lane & 15, quad = lane >> 4;

  __shared__ __align__(16) u16 As[2][8192];         // 2 x 16 KB A k-slices (256 rows x 32)
  __shared__ __align__(16) u16 Bs[8448];            // [r4][col66][c32] = 16896 B
  __shared__ float sig_l[256];

  const int y0 = p_blk * 2;
  const size_t xt_base = ((size_t)(bl * 16) * XT_CGELEMS) + (size_t)y0 * XT_ROWELEMS;
  const size_t w_base = (size_t)og * (256 * 32);    // batch-independent

  auto stage_b = [&](int cgi) {                     // 16896 B contiguous, async
    const char* g = (const char*)(xt + xt_base + (size_t)cgi * XT_CGELEMS);
    for (int r = wave; r < 16; r += 4)
      GLDS(g + r * 1024 + lane * 16, (char*)Bs + r * 1024);
    if (wave == 0 && lane < 32)                     // 512 B tail
      GLDS(g + 16384 + lane * 16, (char*)Bs + 16384);
  };
  auto stage_a = [&](int t, int cgi, int buf) {     // 16 KB contiguous, async (4 GLDS/wave)
    const char* g = (const char*)(wb + w_base + (size_t)(t * 16 + cgi) * 16384);
    for (int r = wave; r < 16; r += 4)
      GLDS(g + r * 1024 + lane * 16, (char*)As[buf] + r * 1024);
  };

  // loop-invariant swizzled fragment addresses (verified; conflicts = 0)
  int aoff[8];
#pragma unroll
  for (int mt = 0; mt < 8; ++mt) {
    int row = wm_off + mt * 16 + l15;               // local o-row; global o = og*256+row
    aoff[mt] = row * 32 + ((quad ^ ((row >> 1) & 3)) << 3);
  }
  int pr[4], pc[4];
#pragma unroll
  for (int nt = 0; nt < 4; ++nt) {
    int p = wn_off + nt * 16 + l15;
    pr[nt] = p >> 6; pc[nt] = p & 63;
  }

  floatx4 acc[8][4];
  const floatx4 zf = {0.f, 0.f, 0.f, 0.f};
#pragma unroll
  for (int mt = 0; mt < 8; ++mt)
#pragma unroll
    for (int nt = 0; nt < 4; ++nt) acc[mt][nt] = zf;

  sig_l[tid] = sig[bl * 512 + og * 256 + tid];      // hoisted preload (synced below)
  stage_b(0);
  stage_a(0, 0, 0);
  __syncthreads();                                  // vmcnt drain + sig_l visible

#pragma unroll 1
  for (int cgi = 0; cgi < 16; ++cgi) {
#pragma unroll 1
    for (int t = 0; t < 9; ++t) {
      const int cur = (cgi * 9 + t) & 1, nxt = cur ^ 1;
      const bool last = (cgi == 15 && t == 8);
      const bool cgb = (t == 8 && cgi < 15);        // cg boundary
      if (!last) stage_a(t < 8 ? t + 1 : 0, t < 8 ? cgi : cgi + 1, nxt);  // async prefetch

      const int ky = t / 3, kx = t - ky * 3;
      s16x8 afr[8], bfr[4];
      const u16* Ab = As[cur];
#pragma unroll
      for (int nt = 0; nt < 4; ++nt) {              // B[n=lane&15][k=quad*8+j], swizzled
        int r = pr[nt] + ky, c = pc[nt] + kx;
        bfr[nt] = *(const s16x8*)&Bs[(r * 66 + c) * 32 + ((quad ^ ((c >> 1) & 3)) << 3)];
      }
#pragma unroll
      for (int mt = 0; mt < 8; ++mt)                // A[m=lane&15][k=quad*8+j], swizzled
        afr[mt] = *(const s16x8*)&Ab[aoff[mt]];
#pragma unroll
      for (int mt = 0; mt < 8; ++mt)
#pragma unroll
        for (int nt = 0; nt < 4; ++nt)
          acc[mt][nt] = __builtin_amdgcn_mfma_f32_16x16x32_bf16(
              afr[mt], bfr[nt], acc[mt][nt], 0, 0, 0);

      if (cgb) {
        __syncthreads();                            // all waves done reading Bs
        stage_b(cgi + 1);                           // async restage
      }
      if (!last) __syncthreads();                   // drains DMA; LDS visible
    }
  }

  // epilogue: C/D layout col=lane&15, row=quad*4+reg (m89-verified); apply sigma_inv
  float* outp = out + ((size_t)bl * 512 + og * 256) * 4096 + p_blk * 128;
#pragma unroll
  for (int mt = 0; mt < 8; ++mt)
#pragma unroll
    for (int nt = 0; nt < 4; ++nt) {
      int n = wn_off + nt * 16 + l15;
#pragma unroll
      for (int r = 0; r < 4; ++r) {
        int m = wm_off + mt * 16 + quad * 4 + r;
        outp[(size_t)m * 4096 + n] = acc[mt][nt][r] * sig_l[m];
      }
    }
}

// ---------------- fallback: zero-workspace direct conv (known-PASS) ----------------
__global__ __launch_bounds__(256) void conv_direct(
    const float* __restrict__ fm, const float* __restrict__ style,
    const float* __restrict__ w, float* __restrict__ out)
{
  const int o = blockIdx.x, b = blockIdx.y, tid = threadIdx.x;
  __shared__ float swm[4608];
  __shared__ float red[4];
  const float gain = 0.014731391f;
  const float* wo = w + (size_t)o * 4608;
  const float* st = style + (size_t)b * 512;
  float ss = 0.f;
#pragma unroll
  for (int j = 0; j < 18; ++j) {
    int idx = j * 256 + tid;
    float v = wo[idx] * gain * st[idx / 9];
    swm[idx] = v;
    ss += v * v;
  }
#pragma unroll
  for (int off = 32; off > 0; off >>= 1) ss += __shfl_down(ss, off, 64);
  if ((tid & 63) == 0) red[tid >> 6] = ss;
  __syncthreads();
  const float sinv = rsqrtf(red[0] + red[1] + red[2] + red[3] + 1e-8f);

  const int y = tid >> 2, x0 = (tid & 3) * 16;
  float acc[16];
#pragma unroll
  for (int i = 0; i < 16; ++i) acc[i] = 0.f;
  const float* fb = fm + (size_t)b * 512 * 4096;
  for (int ci = 0; ci < 512; ++ci) {
    const float* fc = fb + (size_t)ci * 4096;
    const float* wr = swm + ci * 9;
#pragma unroll
    for (int ky = 0; ky < 3; ++ky) {
      int yy = y + ky - 1;
      if (yy < 0 || yy > 63) continue;
      const float* frow = fc + yy * 64;
#pragma unroll
      for (int kx = 0; kx < 3; ++kx) {
        float wv = wr[ky * 3 + kx];
#pragma unroll
        for (int i = 0; i < 16; ++i) {
          int xx = x0 + i + kx - 1;
          float xv = (xx >= 0 && xx < 64) ? frow[xx] : 0.f;
          acc[i] += wv * xv;
        }
      }
    }
  }
  float* op = out + ((size_t)b * 512 + o) * 4096 + y * 64 + x0;
#pragma unroll
  for (int i = 0; i < 16; ++i) op[i] = acc[i] * sinv;
}

extern "C" void kernel_launch(void* const* d_in, const int* in_sizes, int n_in,
                              void* d_out, int out_size, void* d_ws, size_t ws_size,
                              hipStream_t stream) {
  const float* fm = (const float*)d_in[0];     // (8,512,64,64) fp32
  const float* style = (const float*)d_in[1];  // (8,512) fp32
  const float* w = (const float*)d_in[2];      // (512,512,3,3) fp32
  float* out = (float*)d_out;                  // (8,512,64,64) fp32

  const size_t need = 8ull * XT_PB + WB_B + SIG_B;   // 40.4 MB
  if (ws_size < need) {                        // workspace too small: direct path
    conv_direct<<<dim3(512, 8), 256, 0, stream>>>(fm, style, w, out);
    return;
  }

  u16* xt = (u16*)d_ws;
  u16* wb = (u16*)((char*)d_ws + 8ull * XT_PB);
  float* sig = (float*)((char*)wb + WB_B);

  prep_fused<<<dim3(8704), 256, 0, stream>>>(fm, w, style, xt, wb, sig);
  conv_mfma<<<dim3(512), 256, 0, stream>>>(wb, xt, sig, out);
}

// Round 16
// 263.180 us; speedup vs baseline: 1.0124x; 1.0124x over previous
//
#include <hip/hip_runtime.h>

typedef unsigned short u16;
typedef __attribute__((ext_vector_type(8))) short s16x8;   // 8 x bf16 frag (verified form)
typedef __attribute__((ext_vector_type(4))) float floatx4;

// xt (per batch): [cg=16][row=66][col=66][c32=32] bf16, spatial-padded NCHW32c,
// holding x * style (style folded in). SWIZZLED: 16B slot ^= (col>>1)&3.
#define XT_ROWELEMS 2112                 // 66*32
#define XT_CGELEMS  139392               // 66*66*32
#define XT_PB       4460544ull           // 16*66*66*32*2 bytes per batch
// wb (batch-INDEPENDENT): [t=9][cg=16][o512=512][c32=32] bf16 = w*gain.
// SWIZZLED: within each 64B o-row, c32 index ^= ((o>>1)&3)<<3
#define WB_B        4718592ull           // 9*16*512*32*2 bytes
#define SIG_B       16384ull             // sigma_inv[8][512] fp32

// async global->LDS DMA, 16B per lane; lds dest = wave-uniform base + lane*16
#define GLDS(gp, lp) __builtin_amdgcn_global_load_lds(                      \
    (const __attribute__((address_space(1))) void*)(gp),                    \
    (__attribute__((address_space(3))) void*)(lp), 16, 0, 0)

__device__ __forceinline__ u16 f2bf(float f) {
  union { float f; unsigned u; } x; x.f = f;
  unsigned r = x.u + 0x7fffu + ((x.u >> 16) & 1u);
  return (u16)(r >> 16);
}

// ---------------- fused producer: transpose(x*style) + weight-convert + sigma ----------------
// grid 8704, 256 threads. Roles: bid%17==0 -> W (512 blocks, one per o);
// else T (8192 blocks: 1024 tiles x 8 batches). Interleaved for co-residency.
// W role: wb[o] = bf16(w[o]*gain) in conv layout (swizzled), PLUS
//   sigma_inv[b][o] = rsqrt(sum_{ci,t}(w*gain*style[b,ci])^2 + 1e-8) for all 8 b
//   (exact reference arithmetic, fp32). 8x less modulate-class work than pre-R14.
// T role: xt[b] = bf16(fm[b,ci] * style[b,ci]) — conv is bilinear, so
//   conv(x*s, w*gain)*sinv == conv(x, w*gain*s*sinv) exactly.
__global__ __launch_bounds__(256) void prep_fused(
    const float* __restrict__ fm, const float* __restrict__ w,
    const float* __restrict__ style, u16* __restrict__ xt,
    u16* __restrict__ wb, float* __restrict__ sig)
{
  __shared__ __align__(16) char smraw[34944];     // W: 4608+4096+32 f32 | T: 64x40 u16
  const int bid = blockIdx.x;
  const int tid = threadIdx.x;
  const int g = bid / 17, rrole = bid - g * 17;

  if (rrole != 0) {
    // ---------- T role: transpose with style fold ----------
    u16* sm16 = (u16*)smraw;                      // [x=64][ci=32] pad 40
    const int ti = g * 16 + (rrole - 1);          // [0, 8192)
    const int y = ti & 63, cgi = (ti >> 6) & 15, bl = ti >> 10;
    const float* src = fm + (((size_t)bl * 512 + cgi * 32) * 64 + y) * 64;
    const float* stp = style + bl * 512 + cgi * 32;
    const int x4 = (tid & 15) * 4;
#pragma unroll
    for (int it = 0; it < 2; ++it) {
      int ci = (tid >> 4) + it * 16;
      float sval = stp[ci];
      float4 v = *(const float4*)&src[(size_t)ci * 4096 + x4];   // 16B/lane coalesced
      sm16[(x4 + 0) * 40 + ci] = f2bf(v.x * sval);
      sm16[(x4 + 1) * 40 + ci] = f2bf(v.y * sval);
      sm16[(x4 + 2) * 40 + ci] = f2bf(v.z * sval);
      sm16[(x4 + 3) * 40 + ci] = f2bf(v.w * sval);
    }

    u16* cgbase = xt + (size_t)(bl * 16 + cgi) * XT_CGELEMS;
    const uint4 z = {0u, 0u, 0u, 0u};
    u16* rowb = cgbase + (size_t)(y + 1) * XT_ROWELEMS;
    if (tid < 4)              ((uint4*)rowb)[tid] = z;                  // col 0
    else if (tid < 8)         ((uint4*)(rowb + 65 * 32))[tid - 4] = z;  // col 65
    if (y == 0)  for (int i = tid; i < 264; i += 256) ((uint4*)cgbase)[i] = z;
    if (y == 63) for (int i = tid; i < 264; i += 256) ((uint4*)(cgbase + 65 * XT_ROWELEMS))[i] = z;

    __syncthreads();
    const int x = tid >> 2;
    uint4 u = *(const uint4*)&sm16[x * 40 + (tid & 3) * 8];       // one ds_read_b128
    const int col = 1 + x;
    const int slot = (tid & 3) ^ ((col >> 1) & 3);                // pre-swizzle
    ((uint4*)rowb)[col * 4 + slot] = u;
  } else {
    // ---------- W role: one o; wb = bf16(w*gain); sigma_inv for 8 batches ----------
    float* sv = (float*)smraw;                    // 4608: w[o]*gain, idx = ci*9 + t
    float* s2 = sv + 4608;                        // 4096: style^2 for 8 batches
    float* red = s2 + 4096;                       // 32: per-wave partials x 8 b
    const int o = g;
    const float gain = 0.014731391f;              // 1/sqrt(512*9)
    const float* wo = w + (size_t)o * 4608;
    for (int i = tid; i < 4096; i += 256) { float s = style[i]; s2[i] = s * s; }
    __syncthreads();

    float ss[8];
#pragma unroll
    for (int b = 0; b < 8; ++b) ss[b] = 0.f;
#pragma unroll
    for (int j = 0; j < 5; ++j) {                 // 1152 float4 slots over 256 thr
      int s4 = j * 256 + tid;
      if (s4 < 1152) {
        float4 v = *(const float4*)&wo[s4 * 4];   // 16B/lane coalesced
        int i0 = s4 * 4;
        int c0 = i0 / 9, rem = i0 - c0 * 9;       // ci of elem 0
        int ci1 = c0 + (rem + 1 >= 9), ci2 = c0 + (rem + 2 >= 9), ci3 = c0 + (rem + 3 >= 9);
        floatx4 wv = {v.x * gain, v.y * gain, v.z * gain, v.w * gain};
        ((floatx4*)sv)[s4] = wv;                  // ds_write_b128
        float q0 = wv[0] * wv[0], q1 = wv[1] * wv[1];
        float q2 = wv[2] * wv[2], q3 = wv[3] * wv[3];
#pragma unroll
        for (int b = 0; b < 8; ++b) {
          const float* sb = s2 + b * 512;
          ss[b] += q0 * sb[c0] + q1 * sb[ci1] + q2 * sb[ci2] + q3 * sb[ci3];
        }
      }
    }
    const int lane = tid & 63, wave = tid >> 6;
#pragma unroll
    for (int b = 0; b < 8; ++b) {
#pragma unroll
      for (int off = 32; off > 0; off >>= 1) ss[b] += __shfl_down(ss[b], off, 64);
    }
    if (lane == 0)
#pragma unroll
      for (int b = 0; b < 8; ++b) red[wave * 8 + b] = ss[b];
    __syncthreads();
    if (tid < 8) {
      float t8 = red[tid] + red[8 + tid] + red[16 + tid] + red[24 + tid];
      sig[tid * 512 + o] = rsqrtf(t8 + 1e-8f);    // sigma_inv[b][o]
    }

    // wb store: [t][cg][o][c32], swizzled o-row; NO style, NO sinv (hoisted out)
    const int axor = ((o >> 1) & 3) << 3;
    u16* base = wb + (size_t)o * 32;
    const int c0 = tid * 2;                       // even -> XOR keeps pair adjacent
    const int pos = (c0 & 31) ^ axor;             // even (axor has no bit0)
#pragma unroll
    for (int t = 0; t < 9; ++t) {                 // 9 paired u32 stores
      unsigned lo = f2bf(sv[c0 * 9 + t]);
      unsigned hi = f2bf(sv[(c0 + 1) * 9 + t]);
      *(unsigned*)(base + ((size_t)(t * 16 + (c0 >> 5))) * 16384 + pos) = lo | (hi << 16);
    }
  }
}

// ---------------- conv: R6-verified body + sigma epilogue (session best: 261.6 total, R14) ----------------
// 256x128 C tile, 256 threads = 4 waves, wave tile 128x64, 16x16x32 MFMA, plain
// __syncthreads discipline. Cross-session ledger: this form = 158.4/162.4/160.3 us;
// counted-vmcnt = 157.8/170.2; 4-phase = 183; 2-fat-phase = 191; all other levers
// (occupancy, tile, LDS traffic, barriers, MFMA shape) null — schedule closed.
// wb is batch-independent (L2-resident; FETCH == xt only). R15's epsilon edits
// reverted (neutral-negative within noise); this is R14 byte-exact.
__global__ __launch_bounds__(256, 2) void conv_mfma(
    const u16* __restrict__ wb, const u16* __restrict__ xt,
    const float* __restrict__ sig, float* __restrict__ out)
{
  const int id = blockIdx.x;
  const int bl = id & 7;                            // same batch -> same XCD (round robin)
  const int rest = id >> 3;
  const int og = rest & 1, p_blk = rest >> 1;       // og: 256-row M chunk; p_blk: 128 px
  const int tid = threadIdx.x;
  const int lane = tid & 63, wave = tid >> 6;
  const int wm_off = (wave & 1) * 128, wn_off = (wave >> 1) * 64;
  const int l15 = lane & 15, quad = lane >> 4;

  __shared__ __align__(16) u16 As[2][8192];         // 2 x 16 KB A k-slices (256 rows x 32)
  __shared__ __align__(16) u16 Bs[8448];            // [r4][col66][c32] = 16896 B
  __shared__ float sig_l[256];

  const int y0 = p_blk * 2;
  const size_t xt_base = ((size_t)(bl * 16) * XT_CGELEMS) + (size_t)y0 * XT_ROWELEMS;
  const size_t w_base = (size_t)og * (256 * 32);    // batch-independent

  auto stage_b = [&](int cgi) {                     // 16896 B contiguous, async
    const char* g = (const char*)(xt + xt_base + (size_t)cgi * XT_CGELEMS);
    for (int r = wave; r < 16; r += 4)
      GLDS(g + r * 1024 + lane * 16, (char*)Bs + r * 1024);
    if (wave == 0 && lane < 32)                     // 512 B tail
      GLDS(g + 16384 + lane * 16, (char*)Bs + 16384);
  };
  auto stage_a = [&](int t, int cgi, int buf) {     // 16 KB contiguous, async (4 GLDS/wave)
    const char* g = (const char*)(wb + w_base + (size_t)(t * 16 + cgi) * 16384);
    for (int r = wave; r < 16; r += 4)
      GLDS(g + r * 1024 + lane * 16, (char*)As[buf] + r * 1024);
  };

  // loop-invariant swizzled fragment addresses (verified; conflicts = 0)
  int aoff[8];
#pragma unroll
  for (int mt = 0; mt < 8; ++mt) {
    int row = wm_off + mt * 16 + l15;               // local o-row; global o = og*256+row
    aoff[mt] = row * 32 + ((quad ^ ((row >> 1) & 3)) << 3);
  }
  int pr[4], pc[4];
#pragma unroll
  for (int nt = 0; nt < 4; ++nt) {
    int p = wn_off + nt * 16 + l15;
    pr[nt] = p >> 6; pc[nt] = p & 63;
  }

  floatx4 acc[8][4];
  const floatx4 zf = {0.f, 0.f, 0.f, 0.f};
#pragma unroll
  for (int mt = 0; mt < 8; ++mt)
#pragma unroll
    for (int nt = 0; nt < 4; ++nt) acc[mt][nt] = zf;

  stage_b(0);
  stage_a(0, 0, 0);
  __syncthreads();                                  // vmcnt drain -> data visible

#pragma unroll 1
  for (int cgi = 0; cgi < 16; ++cgi) {
#pragma unroll 1
    for (int t = 0; t < 9; ++t) {
      const int cur = (cgi * 9 + t) & 1, nxt = cur ^ 1;
      const bool last = (cgi == 15 && t == 8);
      const bool cgb = (t == 8 && cgi < 15);        // cg boundary
      if (!last) stage_a(t < 8 ? t + 1 : 0, t < 8 ? cgi : cgi + 1, nxt);  // async prefetch

      const int ky = t / 3, kx = t - ky * 3;
      s16x8 afr[8], bfr[4];
      const u16* Ab = As[cur];
#pragma unroll
      for (int nt = 0; nt < 4; ++nt) {              // B[n=lane&15][k=quad*8+j], swizzled
        int r = pr[nt] + ky, c = pc[nt] + kx;
        bfr[nt] = *(const s16x8*)&Bs[(r * 66 + c) * 32 + ((quad ^ ((c >> 1) & 3)) << 3)];
      }
#pragma unroll
      for (int mt = 0; mt < 8; ++mt)                // A[m=lane&15][k=quad*8+j], swizzled
        afr[mt] = *(const s16x8*)&Ab[aoff[mt]];
#pragma unroll
      for (int mt = 0; mt < 8; ++mt)
#pragma unroll
        for (int nt = 0; nt < 4; ++nt)
          acc[mt][nt] = __builtin_amdgcn_mfma_f32_16x16x32_bf16(
              afr[mt], bfr[nt], acc[mt][nt], 0, 0, 0);

      if (cgb) {
        __syncthreads();                            // all waves done reading Bs
        stage_b(cgi + 1);                           // async restage
      }
      __syncthreads();                              // drains DMA; LDS visible
    }
  }

  // sigma preload: rows og*256 .. og*256+255 of batch bl
  sig_l[tid] = sig[bl * 512 + og * 256 + tid];
  __syncthreads();

  // epilogue: C/D layout col=lane&15, row=quad*4+reg (m89-verified); apply sigma_inv
  float* outp = out + ((size_t)bl * 512 + og * 256) * 4096 + p_blk * 128;
#pragma unroll
  for (int mt = 0; mt < 8; ++mt)
#pragma unroll
    for (int nt = 0; nt < 4; ++nt) {
      int n = wn_off + nt * 16 + l15;
#pragma unroll
      for (int r = 0; r < 4; ++r) {
        int m = wm_off + mt * 16 + quad * 4 + r;
        outp[(size_t)m * 4096 + n] = acc[mt][nt][r] * sig_l[m];
      }
    }
}

// ---------------- fallback: zero-workspace direct conv (known-PASS) ----------------
__global__ __launch_bounds__(256) void conv_direct(
    const float* __restrict__ fm, const float* __restrict__ style,
    const float* __restrict__ w, float* __restrict__ out)
{
  const int o = blockIdx.x, b = blockIdx.y, tid = threadIdx.x;
  __shared__ float swm[4608];
  __shared__ float red[4];
  const float gain = 0.014731391f;
  const float* wo = w + (size_t)o * 4608;
  const float* st = style + (size_t)b * 512;
  float ss = 0.f;
#pragma unroll
  for (int j = 0; j < 18; ++j) {
    int idx = j * 256 + tid;
    float v = wo[idx] * gain * st[idx / 9];
    swm[idx] = v;
    ss += v * v;
  }
#pragma unroll
  for (int off = 32; off > 0; off >>= 1) ss += __shfl_down(ss, off, 64);
  if ((tid & 63) == 0) red[tid >> 6] = ss;
  __syncthreads();
  const float sinv = rsqrtf(red[0] + red[1] + red[2] + red[3] + 1e-8f);

  const int y = tid >> 2, x0 = (tid & 3) * 16;
  float acc[16];
#pragma unroll
  for (int i = 0; i < 16; ++i) acc[i] = 0.f;
  const float* fb = fm + (size_t)b * 512 * 4096;
  for (int ci = 0; ci < 512; ++ci) {
    const float* fc = fb + (size_t)ci * 4096;
    const float* wr = swm + ci * 9;
#pragma unroll
    for (int ky = 0; ky < 3; ++ky) {
      int yy = y + ky - 1;
      if (yy < 0 || yy > 63) continue;
      const float* frow = fc + yy * 64;
#pragma unroll
      for (int kx = 0; kx < 3; ++kx) {
        float wv = wr[ky * 3 + kx];
#pragma unroll
        for (int i = 0; i < 16; ++i) {
          int xx = x0 + i + kx - 1;
          float xv = (xx >= 0 && xx < 64) ? frow[xx] : 0.f;
          acc[i] += wv * xv;
        }
      }
    }
  }
  float* op = out + ((size_t)b * 512 + o) * 4096 + y * 64 + x0;
#pragma unroll
  for (int i = 0; i < 16; ++i) op[i] = acc[i] * sinv;
}

extern "C" void kernel_launch(void* const* d_in, const int* in_sizes, int n_in,
                              void* d_out, int out_size, void* d_ws, size_t ws_size,
                              hipStream_t stream) {
  const float* fm = (const float*)d_in[0];     // (8,512,64,64) fp32
  const float* style = (const float*)d_in[1];  // (8,512) fp32
  const float* w = (const float*)d_in[2];      // (512,512,3,3) fp32
  float* out = (float*)d_out;                  // (8,512,64,64) fp32

  const size_t need = 8ull * XT_PB + WB_B + SIG_B;   // 40.4 MB
  if (ws_size < need) {                        // workspace too small: direct path
    conv_direct<<<dim3(512, 8), 256, 0, stream>>>(fm, style, w, out);
    return;
  }

  u16* xt = (u16*)d_ws;
  u16* wb = (u16*)((char*)d_ws + 8ull * XT_PB);
  float* sig = (float*)((char*)wb + WB_B);

  prep_fused<<<dim3(8704), 256, 0, stream>>>(fm, w, style, xt, wb, sig);
  conv_mfma<<<dim3(512), 256, 0, stream>>>(wb, xt, sig, out);
}